// Round 4
// baseline (165538.599 us; speedup 1.0000x reference)
//
#include <hip/hip_runtime.h>
#include <cstdint>
#include <cfloat>
#include <cmath>

#define NB 64
#define LL 2048
#define HH 512
#define VV 34
#define TT 600
#define GRID 256
#define BLKT 512

// JAX threefry_partitionable (default since jax 0.4.36): bits = o0 ^ o1. VERIFIED round 2.
#define PARTITIONABLE 1

__device__ __forceinline__ float sigm_(float x){ return 1.0f/(1.0f+expf(-x)); }
__device__ __forceinline__ unsigned rotl_(unsigned x, int r){ return (x<<r)|(x>>(32-r)); }

// Threefry-2x32, 20 rounds, exactly JAX's schedule.
__device__ __forceinline__ void tf2x32_(unsigned k0, unsigned k1, unsigned x0, unsigned x1,
                                        unsigned &o0, unsigned &o1){
  unsigned ks2 = k0 ^ k1 ^ 0x1BD11BDAu;
  x0 += k0; x1 += k1;
  x0+=x1; x1=rotl_(x1,13); x1^=x0;
  x0+=x1; x1=rotl_(x1,15); x1^=x0;
  x0+=x1; x1=rotl_(x1,26); x1^=x0;
  x0+=x1; x1=rotl_(x1, 6); x1^=x0;
  x0+=k1; x1+=ks2+1u;
  x0+=x1; x1=rotl_(x1,17); x1^=x0;
  x0+=x1; x1=rotl_(x1,29); x1^=x0;
  x0+=x1; x1=rotl_(x1,16); x1^=x0;
  x0+=x1; x1=rotl_(x1,24); x1^=x0;
  x0+=ks2; x1+=k0+2u;
  x0+=x1; x1=rotl_(x1,13); x1^=x0;
  x0+=x1; x1=rotl_(x1,15); x1^=x0;
  x0+=x1; x1=rotl_(x1,26); x1^=x0;
  x0+=x1; x1=rotl_(x1, 6); x1^=x0;
  x0+=k0; x1+=k1+3u;
  x0+=x1; x1=rotl_(x1,17); x1^=x0;
  x0+=x1; x1=rotl_(x1,29); x1^=x0;
  x0+=x1; x1=rotl_(x1,16); x1^=x0;
  x0+=x1; x1=rotl_(x1,24); x1^=x0;
  x0+=k1; x1+=ks2+4u;
  x0+=x1; x1=rotl_(x1,13); x1^=x0;
  x0+=x1; x1=rotl_(x1,15); x1^=x0;
  x0+=x1; x1=rotl_(x1,26); x1^=x0;
  x0+=x1; x1=rotl_(x1, 6); x1^=x0;
  x0+=ks2; x1+=k0+5u;
  o0 = x0; o1 = x1;
}

__global__ __launch_bounds__(BLKT, 2) void speller_kernel(
    const float* __restrict__ seq, const int* __restrict__ slen,
    const float* __restrict__ Ech, const float* __restrict__ Wkey,
    const float* __restrict__ Wval, const float* __restrict__ bval,
    const float* __restrict__ Wih, const float* __restrict__ Whh,
    const float* __restrict__ bih, const float* __restrict__ bhh,
    const float* __restrict__ Wcdn, const float* __restrict__ bcdn,
    int* __restrict__ out, float* __restrict__ ws, int MS, int CH)
{
  const int tid = threadIdx.x;
  const int bid = blockIdx.x;
  const int gid = bid*BLKT + tid;

  // ---- workspace layout ----
  float* biasf = ws;                         // [2048]  b_ih + b_hh
  float* h0    = biasf + 2048;               // [NB*HH]
  float* h1    = h0 + NB*HH;                 // [NB*HH]
  float* cb    = h1 + NB*HH;                 // [NB*HH]
  float* ctx   = cb + NB*HH;                 // [NB*HH]
  float* qt    = ctx + NB*HH;                // [NB*HH]
  float* pm    = qt + NB*HH;                 // [NB*MS]
  float* ps    = pm + NB*MS;                 // [NB*MS]
  float* pacc  = ps + NB*MS;                 // [NB*MS*HH]
  int*   iw    = (int*)(pacc + (size_t)NB*MS*HH);
  int*   yv    = iw;                          // [64]
  int*   pref  = iw + 64;                     // [65]
  int*   nTotP = iw + 129;
  int*   cntP  = iw + 130;                    // chunk counter (memset 0 per launch)
  int*   cntB  = iw + 131;                    // barrier counter (memset 0 per launch)

  __shared__ float sXs[128*65];
  __shared__ float sRed[8*8*64];
  __shared__ float sGate[8*64];
  __shared__ float sAcc[8*512];
  __shared__ float sWm[8], sWs[8], sWf[8];
  __shared__ float sEb[512];
  __shared__ float sHs[512];
  __shared__ float sCt[512];
  __shared__ float sP[34*8];
  __shared__ float sZ[34];
  __shared__ float sAm[32], sAs[32], sAf[32];
  __shared__ float sSc[2];
  __shared__ int   sChunk;
  __shared__ int   sPref[65];
  __shared__ int   sLenA[64];

  // ---- lightweight grid barrier (agent scope), monotonic epoch, cntB=0 per launch ----
  int epoch = 0;
  auto gsync = [&](){
    __syncthreads();              // drain this block's stores to L2
    epoch++;
    if (tid == 0){
      __threadfence();            // L2 writeback (agent scope release)
      __hip_atomic_fetch_add(cntB, 1, __ATOMIC_RELAXED, __HIP_MEMORY_SCOPE_AGENT);
      while (__hip_atomic_load(cntB, __ATOMIC_RELAXED, __HIP_MEMORY_SCOPE_AGENT) < epoch*GRID)
        __builtin_amdgcn_s_sleep(2);
      __threadfence();            // L2 invalidate (agent scope acquire)
    }
    __syncthreads();
  };

  // ================= P0: one-time precompute =================
  {
    if (gid < NB*HH){ h0[gid]=0.f; h1[gid]=0.f; cb[gid]=0.f; qt[gid]=0.f; }
    if (gid < NB) yv[gid] = 0;  // SOS
    if (gid < 2048) biasf[gid] = bih[gid] + bhh[gid];
    if (gid == 0){
      int acc = 0; pref[0] = 0;
      for (int b=0;b<NB;b++){
        int ln = slen[b]; if (ln < 1) ln = 1; if (ln > LL) ln = LL;
        acc += (ln + CH - 1)/CH;
        pref[b+1] = acc;
      }
      *nTotP = acc;
    }
  }

  // ================= phase lambdas (math identical to verified round-2) =================

  // A: gates = Wih*[emb(y); ctx] + Whh*h + biasf ; LSTM update -> c, hw
  auto phaseA = [&](const float* hr, float* hw){
    const int k0 = bid*2;
    const int w = tid >> 6, lane = tid & 63;
    float acc[8];
    #pragma unroll
    for (int jj=0;jj<8;jj++) acc[jj]=0.f;
    for (int kt=0; kt<12; kt++){
      __syncthreads();
      #pragma unroll
      for (int r=0;r<16;r++){
        int e = r*512 + tid;
        int b = e >> 7, kk = e & 127;
        int mm = kt*128 + kk;
        float v;
        if (kt < 4)      v = Ech[(size_t)yv[b]*HH + mm];
        else if (kt < 8) v = ctx[b*HH + (mm-512)];
        else             v = hr[b*HH + (mm-1024)];
        sXs[kk*65 + b] = v;
      }
      __syncthreads();
      const float* wrow[8];
      #pragma unroll
      for (int jj=0;jj<8;jj++){
        int j = (jj>>1)*512 + k0 + (jj&1);
        if (kt < 8) wrow[jj] = Wih + (size_t)j*1024 + kt*128;
        else        wrow[jj] = Whh + (size_t)j*512  + (kt-8)*128;
      }
      #pragma unroll
      for (int it=0; it<4; it++){
        int kkb = w*16 + it*4;
        float x0 = sXs[(kkb+0)*65 + lane];
        float x1 = sXs[(kkb+1)*65 + lane];
        float x2 = sXs[(kkb+2)*65 + lane];
        float x3 = sXs[(kkb+3)*65 + lane];
        #pragma unroll
        for (int jj=0;jj<8;jj++){
          float4 wv = *(const float4*)(wrow[jj] + kkb);
          acc[jj] += wv.x*x0; acc[jj] += wv.y*x1;
          acc[jj] += wv.z*x2; acc[jj] += wv.w*x3;
        }
      }
    }
    __syncthreads();
    #pragma unroll
    for (int jj=0;jj<8;jj++) sRed[(w*8+jj)*64 + lane] = acc[jj];
    __syncthreads();
    {
      int jj2 = tid >> 6, b2 = tid & 63;
      int j = (jj2>>1)*512 + k0 + (jj2&1);
      float g = biasf[j];
      #pragma unroll
      for (int w2=0; w2<8; w2++) g += sRed[(w2*8+jj2)*64 + b2];
      sGate[jj2*64 + b2] = g;
    }
    __syncthreads();
    if (tid < 128){
      int k01 = tid >> 6, b3 = tid & 63;
      int k = k0 + k01;
      float gi = sGate[(0+k01)*64 + b3];
      float gf = sGate[(2+k01)*64 + b3];
      float gg = sGate[(4+k01)*64 + b3];
      float go = sGate[(6+k01)*64 + b3];
      float co = cb[b3*HH + k];
      float cn = sigm_(gf)*co + sigm_(gi)*tanhf(gg);
      cb[b3*HH + k] = cn;
      hw[b3*HH + k] = sigm_(go)*tanhf(cn);
    }
  };

  // B: qt[b][h'] = sum_k Wkey[k][h'] * h[b][k]   (b_key cancels in softmax)
  auto phaseB = [&](const float* hw){
    if (bid < 32){
      int hcol = tid;
      int b0 = bid*2, b1 = b0+1;
      const float* hp0 = hw + b0*HH;
      const float* hp1 = hw + b1*HH;
      float a0=0.f, a1=0.f;
      for (int k=0;k<512;k++){
        float wv = Wkey[(size_t)k*512 + hcol];
        a0 += wv * hp0[k];
        a1 += wv * hp1[k];
      }
      qt[b0*HH + hcol] = a0;
      qt[b1*HH + hcol] = a1;
    }
  };

  // C: streaming online-softmax attention (1-deep prefetch, from verified round-3)
  auto phaseC = [&](){
    if (tid < 65) sPref[tid] = pref[tid];
    if (tid < 64){ int ln = slen[tid]; if(ln<1)ln=1; if(ln>LL)ln=LL; sLenA[tid]=ln; }
    const int nTot = *nTotP;
    const int w = tid >> 6, lane = tid & 63;
    const float SCALE = 1.0f / sqrtf(512.0f);
    while (true){
      __syncthreads();
      if (tid == 0) sChunk = atomicAdd(cntP, 1);
      __syncthreads();
      int c = sChunk;
      if (c >= nTot) break;
      int b = 0;
      while (sPref[b+1] <= c) b++;
      int slot = c - sPref[b];
      int l0 = slot * CH;
      int lend = min(l0 + CH, sLenA[b]);
      const float4* qp = (const float4*)(qt + b*HH);
      float4 qa = qp[lane], qb = qp[64+lane];
      float m = -FLT_MAX, ss = 0.f;
      float4 aA = make_float4(0,0,0,0), aB = make_float4(0,0,0,0);
      int l = l0 + w;
      float4 ea, eb;
      if (l < lend){
        const float4* rp = (const float4*)(seq + ((size_t)b*LL + l)*HH);
        ea = rp[lane]; eb = rp[64+lane];
      }
      while (l < lend){
        int ln2 = l + 8;
        float4 na, nb;
        if (ln2 < lend){
          const float4* rp2 = (const float4*)(seq + ((size_t)b*LL + ln2)*HH);
          na = rp2[lane]; nb = rp2[64+lane];
        }
        float d = ea.x*qa.x + ea.y*qa.y + ea.z*qa.z + ea.w*qa.w
                + eb.x*qb.x + eb.y*qb.y + eb.z*qb.z + eb.w*qb.w;
        #pragma unroll
        for (int msk=1; msk<64; msk<<=1) d += __shfl_xor(d, msk, 64);
        float sc = d * SCALE;
        float mn = fmaxf(m, sc);
        float r1 = expf(m - mn);
        float w1 = expf(sc - mn);
        ss = ss*r1 + w1;
        aA.x = aA.x*r1 + w1*ea.x; aA.y = aA.y*r1 + w1*ea.y;
        aA.z = aA.z*r1 + w1*ea.z; aA.w = aA.w*r1 + w1*ea.w;
        aB.x = aB.x*r1 + w1*eb.x; aB.y = aB.y*r1 + w1*eb.y;
        aB.z = aB.z*r1 + w1*eb.z; aB.w = aB.w*r1 + w1*eb.w;
        m = mn;
        ea = na; eb = nb; l = ln2;
      }
      ((float4*)(sAcc + w*512))[lane]    = aA;
      ((float4*)(sAcc + w*512))[64+lane] = aB;
      if (lane == 0){ sWm[w] = m; sWs[w] = ss; }
      __syncthreads();
      if (tid == 0){
        float M = sWm[0];
        #pragma unroll
        for (int i=1;i<8;i++) M = fmaxf(M, sWm[i]);
        float S = 0.f;
        #pragma unroll
        for (int i=0;i<8;i++){ float f = expf(sWm[i]-M); sWf[i]=f; S += sWs[i]*f; }
        pm[b*MS+slot] = M; ps[b*MS+slot] = S;
      }
      __syncthreads();
      {
        float v = 0.f;
        #pragma unroll
        for (int i=0;i<8;i++) v += sAcc[i*512 + tid] * sWf[i];
        pacc[((size_t)(b*MS+slot))*HH + tid] = v;
      }
    }
  };

  // D: reduce -> ebar -> ctx ; logits ; gumbel sample ; reset chunk counter
  auto phaseD = [&](int t, const float* hw){
    if (bid < 64){
      const int b = bid;
      const int nsl = pref[b+1] - pref[b];
      if (tid < nsl){ sAm[tid] = pm[b*MS + tid]; sAs[tid] = ps[b*MS + tid]; }
      __syncthreads();
      if (tid == 0){
        float M = sAm[0];
        for (int s=1;s<nsl;s++) M = fmaxf(M, sAm[s]);
        float S = 0.f;
        for (int s=0;s<nsl;s++){ float f = expf(sAm[s]-M); sAf[s] = f; S += sAs[s]*f; }
        sSc[0] = S;
      }
      __syncthreads();
      {
        float S = sSc[0];
        float v = 0.f;
        for (int s=0;s<nsl;s++) v += pacc[((size_t)(b*MS+s))*HH + tid] * sAf[s];
        sEb[tid] = v / S;
        sHs[tid] = hw[b*HH + tid];
      }
      __syncthreads();
      {
        const float4* wr = (const float4*)(Wval + (size_t)tid*HH);
        const float4* er = (const float4*)sEb;
        float a = bval[tid];
        #pragma unroll 4
        for (int i=0;i<HH/4;i++){
          float4 w4 = wr[i], e4 = er[i];
          a += w4.x*e4.x; a += w4.y*e4.y; a += w4.z*e4.z; a += w4.w*e4.w;
        }
        sCt[tid] = a;
        ctx[b*HH + tid] = a;
      }
      __syncthreads();
      if (t >= 0){
        if (tid < 34*8){
          int v = tid >> 3, ks = tid & 7;
          const float* wr = Wcdn + (size_t)v*1024 + ks*128;
          const float* xr = (ks < 4) ? (sHs + ks*128) : (sCt + (ks-4)*128);
          float p = 0.f;
          for (int i=0;i<128;i++) p += wr[i]*xr[i];
          sP[v*8+ks] = p;
        }
        __syncthreads();
        if (tid < 34){
          float lg = bcdn[tid];
          #pragma unroll
          for (int i=0;i<8;i++) lg += sP[tid*8+i];
          unsigned kk0, kk1; tf2x32_(0u, 42u, 0u, (unsigned)t, kk0, kk1);
          int idx = b*34 + tid;
          unsigned o0, o1, bits;
#if PARTITIONABLE
          tf2x32_(kk0, kk1, 0u, (unsigned)idx, o0, o1);
          bits = o0 ^ o1;
#else
          if (idx < 1088){ tf2x32_(kk0, kk1, (unsigned)idx, (unsigned)(idx+1088), o0, o1); bits = o0; }
          else           { tf2x32_(kk0, kk1, (unsigned)(idx-1088), (unsigned)idx, o0, o1); bits = o1; }
#endif
          float f = __uint_as_float((bits>>9) | 0x3f800000u) - 1.0f;
          float u = fmaxf(f, 1.17549435e-38f);
          float gmb = -logf(-logf(u));
          sZ[tid] = lg + gmb;
        }
        __syncthreads();
        if (tid == 0){
          float best = sZ[0]; int bi = 0;
          for (int v2=1; v2<34; v2++){ if (sZ[v2] > best){ best = sZ[v2]; bi = v2; } }
          yv[b] = bi;
          out[b*TT + t] = bi;
        }
      }
    } else if (bid == 64){
      if (tid == 0)
        __hip_atomic_store(cntP, 0, __ATOMIC_RELAXED, __HIP_MEMORY_SCOPE_AGENT);
    }
  };

  // ================= schedule =================
  gsync();
  phaseC();                 // qt == 0 -> uniform weights -> ebar0 = mean(e[:len])
  gsync();
  phaseD(-1, h0);           // ebar/ctx only, no sampling; resets chunk counter
  gsync();
  for (int t = 0; t < TT; t++){
    const float* hr = (t & 1) ? h1 : h0;
    float* hwv      = (t & 1) ? h0 : h1;
    phaseA(hr, hwv);
    gsync();
    phaseB(hwv);
    gsync();
    phaseC();
    gsync();
    phaseD(t, hwv);
    gsync();
  }
}

extern "C" void kernel_launch(void* const* d_in, const int* in_sizes, int n_in,
                              void* d_out, int out_size, void* d_ws, size_t ws_size,
                              hipStream_t stream)
{
  const float* seq  = (const float*)d_in[0];
  const int*   slen = (const int*)d_in[1];
  const float* Ech  = (const float*)d_in[2];
  const float* Wkey = (const float*)d_in[3];
  // d_in[4] = b_key: cancels inside softmax, unused.
  const float* Wval = (const float*)d_in[5];
  const float* bval = (const float*)d_in[6];
  const float* Wih  = (const float*)d_in[7];
  const float* Whh  = (const float*)d_in[8];
  const float* bih  = (const float*)d_in[9];
  const float* bhh  = (const float*)d_in[10];
  const float* Wcdn = (const float*)d_in[11];
  const float* bcdn = (const float*)d_in[12];
  int*   out = (int*)d_out;
  float* ws  = (float*)d_ws;

  int MS = 32;
  while (MS > 1){
    size_t base = 2048 + 5*(size_t)NB*HH;
    size_t need = (base + (size_t)NB*MS*(2 + HH))*4 + 1024;
    if (need <= ws_size) break;
    MS >>= 1;
  }
  int CH = 2048 / MS;

  // byte offset of iw (ints after the float arrays)
  size_t floats_total = 2048 + 5*(size_t)NB*HH + (size_t)NB*MS*(2 + HH);
  size_t cnt_off = floats_total*4 + 130*4;   // cntP, cntB (8 bytes)
  hipMemsetAsync((char*)d_ws + cnt_off, 0, 8, stream);

  void* args[] = { (void*)&seq, (void*)&slen, (void*)&Ech, (void*)&Wkey,
                   (void*)&Wval, (void*)&bval, (void*)&Wih, (void*)&Whh,
                   (void*)&bih, (void*)&bhh, (void*)&Wcdn, (void*)&bcdn,
                   (void*)&out, (void*)&ws, (void*)&MS, (void*)&CH };
  hipLaunchCooperativeKernel((void*)speller_kernel, dim3(GRID), dim3(BLKT),
                             args, 0, stream);
}

// Round 5
// 142562.378 us; speedup vs baseline: 1.1612x; 1.1612x over previous
//
#include <hip/hip_runtime.h>
#include <cstdint>
#include <cfloat>
#include <cmath>

#define NB 64
#define LL 2048
#define HH 512
#define VV 34
#define TT 600
#define GRID 256
#define BLKT 512

// JAX threefry_partitionable (default since jax 0.4.36): bits = o0 ^ o1. VERIFIED round 2.
#define PARTITIONABLE 1

__device__ __forceinline__ float sigm_(float x){ return 1.0f/(1.0f+expf(-x)); }
__device__ __forceinline__ unsigned rotl_(unsigned x, int r){ return (x<<r)|(x>>(32-r)); }

// Threefry-2x32, 20 rounds, exactly JAX's schedule.
__device__ __forceinline__ void tf2x32_(unsigned k0, unsigned k1, unsigned x0, unsigned x1,
                                        unsigned &o0, unsigned &o1){
  unsigned ks2 = k0 ^ k1 ^ 0x1BD11BDAu;
  x0 += k0; x1 += k1;
  x0+=x1; x1=rotl_(x1,13); x1^=x0;
  x0+=x1; x1=rotl_(x1,15); x1^=x0;
  x0+=x1; x1=rotl_(x1,26); x1^=x0;
  x0+=x1; x1=rotl_(x1, 6); x1^=x0;
  x0+=k1; x1+=ks2+1u;
  x0+=x1; x1=rotl_(x1,17); x1^=x0;
  x0+=x1; x1=rotl_(x1,29); x1^=x0;
  x0+=x1; x1=rotl_(x1,16); x1^=x0;
  x0+=x1; x1=rotl_(x1,24); x1^=x0;
  x0+=ks2; x1+=k0+2u;
  x0+=x1; x1=rotl_(x1,13); x1^=x0;
  x0+=x1; x1=rotl_(x1,15); x1^=x0;
  x0+=x1; x1=rotl_(x1,26); x1^=x0;
  x0+=x1; x1=rotl_(x1, 6); x1^=x0;
  x0+=k0; x1+=k1+3u;
  x0+=x1; x1=rotl_(x1,17); x1^=x0;
  x0+=x1; x1=rotl_(x1,29); x1^=x0;
  x0+=x1; x1=rotl_(x1,16); x1^=x0;
  x0+=x1; x1=rotl_(x1,24); x1^=x0;
  x0+=k1; x1+=ks2+4u;
  x0+=x1; x1=rotl_(x1,13); x1^=x0;
  x0+=x1; x1=rotl_(x1,15); x1^=x0;
  x0+=x1; x1=rotl_(x1,26); x1^=x0;
  x0+=x1; x1=rotl_(x1, 6); x1^=x0;
  x0+=ks2; x1+=k0+5u;
  o0 = x0; o1 = x1;
}

__global__ __launch_bounds__(BLKT, 2) void speller_kernel(
    const float* __restrict__ seq, const int* __restrict__ slen,
    const float* __restrict__ Ech, const float* __restrict__ Wkey,
    const float* __restrict__ Wval, const float* __restrict__ bval,
    const float* __restrict__ Wih, const float* __restrict__ Whh,
    const float* __restrict__ bih, const float* __restrict__ bhh,
    const float* __restrict__ Wcdn, const float* __restrict__ bcdn,
    int* __restrict__ out, float* __restrict__ ws, int MS, int CH)
{
  const int tid = threadIdx.x;
  const int bid = blockIdx.x;
  const int gid = bid*BLKT + tid;

  // ---- workspace layout ----
  float* biasf = ws;                         // [2048]  b_ih + b_hh
  float* h0    = biasf + 2048;               // [NB*HH]
  float* h1    = h0 + NB*HH;                 // [NB*HH]
  float* cb    = h1 + NB*HH;                 // [NB*HH]
  float* ctx   = cb + NB*HH;                 // [NB*HH]
  float* pm    = ctx + NB*HH;                // [NB*MS]
  float* ps    = pm + NB*MS;                 // [NB*MS]
  float* pacc  = ps + NB*MS;                 // [NB*MS*HH]
  int*   iw    = (int*)(pacc + (size_t)NB*MS*HH);
  int*   yv    = iw;                          // [64]
  int*   pref  = iw + 64;                     // [65]  chunk prefix; pref[64] = nTot
  int*   bar   = iw + 192;                    // barrier area (memset 0 per launch):
                                              //   bar[0] root; bar[32+g*32] grp; bar[288+g*32] rel

  __shared__ float sXs[128*65];
  __shared__ float sRed[8*8*64];
  __shared__ float sGate[8*64];
  __shared__ float sAcc[8*512];
  __shared__ float sQt[512];
  __shared__ float sWm[8], sWs[8], sWf[8];
  __shared__ float sEb[512];
  __shared__ float sHs[512];
  __shared__ float sCt[512];
  __shared__ float sP[34*8];
  __shared__ float sZ[34];
  __shared__ float sAm[32], sAs[32], sAf[32];
  __shared__ float sSc[2];
  __shared__ int   sPref[65];
  __shared__ int   sLenA[64];

  // ---- hierarchical grid barrier (agent scope), monotonic epochs ----
  int epoch = 0;
  auto gsync = [&](){
    __syncthreads();              // drain this block's stores (write-through L1 -> L2)
    epoch++;
    if (tid == 0){
      __threadfence();            // release: L2 writeback
      const int g = bid >> 5;     // 8 groups of 32 blocks
      int r = __hip_atomic_fetch_add(&bar[32+g*32], 1, __ATOMIC_RELAXED, __HIP_MEMORY_SCOPE_AGENT);
      if (r == epoch*32 - 1){     // last arrival of this group
        int rr = __hip_atomic_fetch_add(&bar[0], 1, __ATOMIC_RELAXED, __HIP_MEMORY_SCOPE_AGENT);
        if (rr == epoch*8 - 1){   // last group overall: release everyone
          #pragma unroll
          for (int i=0;i<8;i++)
            __hip_atomic_store(&bar[288+i*32], epoch, __ATOMIC_RELAXED, __HIP_MEMORY_SCOPE_AGENT);
        } else {
          while (__hip_atomic_load(&bar[288+g*32], __ATOMIC_RELAXED, __HIP_MEMORY_SCOPE_AGENT) < epoch)
            __builtin_amdgcn_s_sleep(8);
        }
      } else {
        while (__hip_atomic_load(&bar[288+g*32], __ATOMIC_RELAXED, __HIP_MEMORY_SCOPE_AGENT) < epoch)
          __builtin_amdgcn_s_sleep(8);
      }
      __threadfence();            // acquire: L2 invalidate
    }
    __syncthreads();
  };

  // ================= P0: one-time precompute =================
  {
    if (gid < NB*HH){ h0[gid]=0.f; h1[gid]=0.f; cb[gid]=0.f; }
    if (gid < NB) yv[gid] = 0;  // SOS
    if (gid < 2048) biasf[gid] = bih[gid] + bhh[gid];
    if (gid == 0){
      int acc = 0; pref[0] = 0;
      for (int b=0;b<NB;b++){
        int ln = slen[b]; if (ln < 1) ln = 1; if (ln > LL) ln = LL;
        acc += (ln + CH - 1)/CH;
        pref[b+1] = acc;
      }
    }
  }

  // ================= phase lambdas (arithmetic identical to verified R2/R4) =================

  // A: gates = Wih*[emb(y); ctx] + Whh*h + biasf ; LSTM update -> c, hw
  auto phaseA = [&](const float* hr, float* hw){
    const int k0 = bid*2;
    const int w = tid >> 6, lane = tid & 63;
    float acc[8];
    #pragma unroll
    for (int jj=0;jj<8;jj++) acc[jj]=0.f;
    for (int kt=0; kt<12; kt++){
      __syncthreads();
      #pragma unroll
      for (int r=0;r<16;r++){
        int e = r*512 + tid;
        int b = e >> 7, kk = e & 127;
        int mm = kt*128 + kk;
        float v;
        if (kt < 4)      v = Ech[(size_t)yv[b]*HH + mm];
        else if (kt < 8) v = ctx[b*HH + (mm-512)];
        else             v = hr[b*HH + (mm-1024)];
        sXs[kk*65 + b] = v;
      }
      __syncthreads();
      const float* wrow[8];
      #pragma unroll
      for (int jj=0;jj<8;jj++){
        int j = (jj>>1)*512 + k0 + (jj&1);
        if (kt < 8) wrow[jj] = Wih + (size_t)j*1024 + kt*128;
        else        wrow[jj] = Whh + (size_t)j*512  + (kt-8)*128;
      }
      #pragma unroll
      for (int it=0; it<4; it++){
        int kkb = w*16 + it*4;
        float x0 = sXs[(kkb+0)*65 + lane];
        float x1 = sXs[(kkb+1)*65 + lane];
        float x2 = sXs[(kkb+2)*65 + lane];
        float x3 = sXs[(kkb+3)*65 + lane];
        #pragma unroll
        for (int jj=0;jj<8;jj++){
          float4 wv = *(const float4*)(wrow[jj] + kkb);
          acc[jj] += wv.x*x0; acc[jj] += wv.y*x1;
          acc[jj] += wv.z*x2; acc[jj] += wv.w*x3;
        }
      }
    }
    __syncthreads();
    #pragma unroll
    for (int jj=0;jj<8;jj++) sRed[(w*8+jj)*64 + lane] = acc[jj];
    __syncthreads();
    {
      int jj2 = tid >> 6, b2 = tid & 63;
      int j = (jj2>>1)*512 + k0 + (jj2&1);
      float g = biasf[j];
      #pragma unroll
      for (int w2=0; w2<8; w2++) g += sRed[(w2*8+jj2)*64 + b2];
      sGate[jj2*64 + b2] = g;
    }
    __syncthreads();
    if (tid < 128){
      int k01 = tid >> 6, b3 = tid & 63;
      int k = k0 + k01;
      float gi = sGate[(0+k01)*64 + b3];
      float gf = sGate[(2+k01)*64 + b3];
      float gg = sGate[(4+k01)*64 + b3];
      float go = sGate[(6+k01)*64 + b3];
      float co = cb[b3*HH + k];
      float cn = sigm_(gf)*co + sigm_(gi)*tanhf(gg);
      cb[b3*HH + k] = cn;
      hw[b3*HH + k] = sigm_(go)*tanhf(cn);
    }
  };

  // C: static chunk range per block; per-batch qt recompute (bit-identical to old phaseB);
  //    streaming online-softmax per chunk (bit-identical to verified R4 inner loop)
  auto phaseC = [&](const float* hr){
    if (tid < 65) sPref[tid] = pref[tid];
    if (tid < 64){ int ln = slen[tid]; if(ln<1)ln=1; if(ln>LL)ln=LL; sLenA[tid]=ln; }
    __syncthreads();
    const int nTot = sPref[64];
    const int w = tid >> 6, lane = tid & 63;
    const float SCALE = 1.0f / sqrtf(512.0f);
    const int start = (bid*nTot)/GRID, end = ((bid+1)*nTot)/GRID;
    int b = 0, bLast = -1;
    for (int c = start; c < end; ++c){
      while (sPref[b+1] <= c) b++;
      int slot = c - sPref[b];
      int l0 = slot * CH;
      int lend = min(l0 + CH, sLenA[b]);
      if (b != bLast){
        __syncthreads();
        // qt[b][tid] = sum_k Wkey[k][tid] * h[b][k]  (same loop order as old phaseB)
        const float* hp = hr + b*HH;
        float a0 = 0.f;
        for (int k=0;k<512;k++)
          a0 += Wkey[(size_t)k*512 + tid] * hp[k];
        sQt[tid] = a0;
        bLast = b;
      }
      __syncthreads();   // sQt visible; protects sAcc/sWf reuse across chunks
      const float4* qp = (const float4*)sQt;
      float4 qa = qp[lane], qb = qp[64+lane];
      float m = -FLT_MAX, ss = 0.f;
      float4 aA = make_float4(0,0,0,0), aB = make_float4(0,0,0,0);
      int l = l0 + w;
      float4 ea, eb;
      if (l < lend){
        const float4* rp = (const float4*)(seq + ((size_t)b*LL + l)*HH);
        ea = rp[lane]; eb = rp[64+lane];
      }
      while (l < lend){
        int ln2 = l + 8;
        float4 na, nb;
        if (ln2 < lend){   // 1-deep prefetch (no arithmetic reorder)
          const float4* rp2 = (const float4*)(seq + ((size_t)b*LL + ln2)*HH);
          na = rp2[lane]; nb = rp2[64+lane];
        }
        float d = ea.x*qa.x + ea.y*qa.y + ea.z*qa.z + ea.w*qa.w
                + eb.x*qb.x + eb.y*qb.y + eb.z*qb.z + eb.w*qb.w;
        #pragma unroll
        for (int msk=1; msk<64; msk<<=1) d += __shfl_xor(d, msk, 64);
        float sc = d * SCALE;
        float mn = fmaxf(m, sc);
        float r1 = expf(m - mn);
        float w1 = expf(sc - mn);
        ss = ss*r1 + w1;
        aA.x = aA.x*r1 + w1*ea.x; aA.y = aA.y*r1 + w1*ea.y;
        aA.z = aA.z*r1 + w1*ea.z; aA.w = aA.w*r1 + w1*ea.w;
        aB.x = aB.x*r1 + w1*eb.x; aB.y = aB.y*r1 + w1*eb.y;
        aB.z = aB.z*r1 + w1*eb.z; aB.w = aB.w*r1 + w1*eb.w;
        m = mn;
        ea = na; eb = nb; l = ln2;
      }
      ((float4*)(sAcc + w*512))[lane]    = aA;
      ((float4*)(sAcc + w*512))[64+lane] = aB;
      if (lane == 0){ sWm[w] = m; sWs[w] = ss; }
      __syncthreads();
      if (tid == 0){
        float M = sWm[0];
        #pragma unroll
        for (int i=1;i<8;i++) M = fmaxf(M, sWm[i]);
        float S = 0.f;
        #pragma unroll
        for (int i=0;i<8;i++){ float f = expf(sWm[i]-M); sWf[i]=f; S += sWs[i]*f; }
        pm[b*MS+slot] = M; ps[b*MS+slot] = S;
      }
      __syncthreads();
      {
        float v = 0.f;
        #pragma unroll
        for (int i=0;i<8;i++) v += sAcc[i*512 + tid] * sWf[i];
        pacc[((size_t)(b*MS+slot))*HH + tid] = v;
      }
    }
  };

  // D: reduce -> ebar -> ctx ; logits ; gumbel sample
  auto phaseD = [&](int t, const float* hw){
    if (bid < 64){
      const int b = bid;
      const int nsl = pref[b+1] - pref[b];
      if (tid < nsl){ sAm[tid] = pm[b*MS + tid]; sAs[tid] = ps[b*MS + tid]; }
      __syncthreads();
      if (tid == 0){
        float M = sAm[0];
        for (int s=1;s<nsl;s++) M = fmaxf(M, sAm[s]);
        float S = 0.f;
        for (int s=0;s<nsl;s++){ float f = expf(sAm[s]-M); sAf[s] = f; S += sAs[s]*f; }
        sSc[0] = S;
      }
      __syncthreads();
      {
        float S = sSc[0];
        float v = 0.f;
        for (int s=0;s<nsl;s++) v += pacc[((size_t)(b*MS+s))*HH + tid] * sAf[s];
        sEb[tid] = v / S;
        sHs[tid] = hw[b*HH + tid];
      }
      __syncthreads();
      {
        const float4* wr = (const float4*)(Wval + (size_t)tid*HH);
        const float4* er = (const float4*)sEb;
        float a = bval[tid];
        #pragma unroll 4
        for (int i=0;i<HH/4;i++){
          float4 w4 = wr[i], e4 = er[i];
          a += w4.x*e4.x; a += w4.y*e4.y; a += w4.z*e4.z; a += w4.w*e4.w;
        }
        sCt[tid] = a;
        ctx[b*HH + tid] = a;
      }
      __syncthreads();
      if (t >= 0){
        if (tid < 34*8){
          int v = tid >> 3, ks = tid & 7;
          const float* wr = Wcdn + (size_t)v*1024 + ks*128;
          const float* xr = (ks < 4) ? (sHs + ks*128) : (sCt + (ks-4)*128);
          float p = 0.f;
          for (int i=0;i<128;i++) p += wr[i]*xr[i];
          sP[v*8+ks] = p;
        }
        __syncthreads();
        if (tid < 34){
          float lg = bcdn[tid];
          #pragma unroll
          for (int i=0;i<8;i++) lg += sP[tid*8+i];
          unsigned kk0, kk1; tf2x32_(0u, 42u, 0u, (unsigned)t, kk0, kk1);
          int idx = b*34 + tid;
          unsigned o0, o1, bits;
#if PARTITIONABLE
          tf2x32_(kk0, kk1, 0u, (unsigned)idx, o0, o1);
          bits = o0 ^ o1;
#else
          if (idx < 1088){ tf2x32_(kk0, kk1, (unsigned)idx, (unsigned)(idx+1088), o0, o1); bits = o0; }
          else           { tf2x32_(kk0, kk1, (unsigned)(idx-1088), (unsigned)idx, o0, o1); bits = o1; }
#endif
          float f = __uint_as_float((bits>>9) | 0x3f800000u) - 1.0f;
          float u = fmaxf(f, 1.17549435e-38f);
          float gmb = -logf(-logf(u));
          sZ[tid] = lg + gmb;
        }
        __syncthreads();
        if (tid == 0){
          float best = sZ[0]; int bi = 0;
          for (int v2=1; v2<34; v2++){ if (sZ[v2] > best){ best = sZ[v2]; bi = v2; } }
          yv[b] = bi;
          out[b*TT + t] = bi;
        }
      }
    }
  };

  // ================= schedule: 3 barriers per step =================
  gsync();
  phaseC(h0);               // h0 == 0 -> qt == 0 bit-exactly -> uniform weights
  gsync();
  phaseD(-1, h0);           // ebar/ctx only, no sampling
  gsync();
  for (int t = 0; t < TT; t++){
    const float* hr = (t & 1) ? h1 : h0;
    float* hwv      = (t & 1) ? h0 : h1;
    phaseA(hr, hwv);
    gsync();
    phaseC(hwv);            // includes per-batch qt recompute (bit-exact vs old phaseB)
    gsync();
    phaseD(t, hwv);
    gsync();
  }
}

extern "C" void kernel_launch(void* const* d_in, const int* in_sizes, int n_in,
                              void* d_out, int out_size, void* d_ws, size_t ws_size,
                              hipStream_t stream)
{
  const float* seq  = (const float*)d_in[0];
  const int*   slen = (const int*)d_in[1];
  const float* Ech  = (const float*)d_in[2];
  const float* Wkey = (const float*)d_in[3];
  // d_in[4] = b_key: cancels inside softmax, unused.
  const float* Wval = (const float*)d_in[5];
  const float* bval = (const float*)d_in[6];
  const float* Wih  = (const float*)d_in[7];
  const float* Whh  = (const float*)d_in[8];
  const float* bih  = (const float*)d_in[9];
  const float* bhh  = (const float*)d_in[10];
  const float* Wcdn = (const float*)d_in[11];
  const float* bcdn = (const float*)d_in[12];
  int*   out = (int*)d_out;
  float* ws  = (float*)d_ws;

  int MS = 32;
  size_t floats_total;
  while (true){
    floats_total = 2048 + 4*(size_t)NB*HH + (size_t)NB*MS*(2 + HH);
    size_t need = (floats_total + 1024)*4;
    if (need <= ws_size || MS == 1) break;
    MS >>= 1;
  }
  int CH = 2048 / MS;

  // zero the barrier area: ints at iw[192 .. 768)
  size_t bar_off = (floats_total + 192)*4;
  hipMemsetAsync((char*)d_ws + bar_off, 0, 576*4, stream);

  void* args[] = { (void*)&seq, (void*)&slen, (void*)&Ech, (void*)&Wkey,
                   (void*)&Wval, (void*)&bval, (void*)&Wih, (void*)&Whh,
                   (void*)&bih, (void*)&bhh, (void*)&Wcdn, (void*)&bcdn,
                   (void*)&out, (void*)&ws, (void*)&MS, (void*)&CH };
  hipLaunchCooperativeKernel((void*)speller_kernel, dim3(GRID), dim3(BLKT),
                             args, 0, stream);
}

// Round 6
// 119370.020 us; speedup vs baseline: 1.3868x; 1.1943x over previous
//
#include <hip/hip_runtime.h>
#include <cstdint>
#include <cfloat>
#include <cmath>

#define NB 64
#define LL 2048
#define HH 512
#define VV 34
#define TT 600
#define GRID 256
#define BLKT 512

// JAX threefry_partitionable (default since jax 0.4.36): bits = o0 ^ o1. VERIFIED round 2.
#define PARTITIONABLE 1

// Coherence-point (cross-XCD) data path: bypasses L1/L2, no fences needed.
#define LDC(p)    __hip_atomic_load((p), __ATOMIC_RELAXED, __HIP_MEMORY_SCOPE_AGENT)
#define STC(p,v)  __hip_atomic_store((p), (v), __ATOMIC_RELAXED, __HIP_MEMORY_SCOPE_AGENT)

__device__ __forceinline__ float sigm_(float x){ return 1.0f/(1.0f+expf(-x)); }
__device__ __forceinline__ unsigned rotl_(unsigned x, int r){ return (x<<r)|(x>>(32-r)); }

// Threefry-2x32, 20 rounds, exactly JAX's schedule.
__device__ __forceinline__ void tf2x32_(unsigned k0, unsigned k1, unsigned x0, unsigned x1,
                                        unsigned &o0, unsigned &o1){
  unsigned ks2 = k0 ^ k1 ^ 0x1BD11BDAu;
  x0 += k0; x1 += k1;
  x0+=x1; x1=rotl_(x1,13); x1^=x0;
  x0+=x1; x1=rotl_(x1,15); x1^=x0;
  x0+=x1; x1=rotl_(x1,26); x1^=x0;
  x0+=x1; x1=rotl_(x1, 6); x1^=x0;
  x0+=k1; x1+=ks2+1u;
  x0+=x1; x1=rotl_(x1,17); x1^=x0;
  x0+=x1; x1=rotl_(x1,29); x1^=x0;
  x0+=x1; x1=rotl_(x1,16); x1^=x0;
  x0+=x1; x1=rotl_(x1,24); x1^=x0;
  x0+=ks2; x1+=k0+2u;
  x0+=x1; x1=rotl_(x1,13); x1^=x0;
  x0+=x1; x1=rotl_(x1,15); x1^=x0;
  x0+=x1; x1=rotl_(x1,26); x1^=x0;
  x0+=x1; x1=rotl_(x1, 6); x1^=x0;
  x0+=k0; x1+=k1+3u;
  x0+=x1; x1=rotl_(x1,17); x1^=x0;
  x0+=x1; x1=rotl_(x1,29); x1^=x0;
  x0+=x1; x1=rotl_(x1,16); x1^=x0;
  x0+=x1; x1=rotl_(x1,24); x1^=x0;
  x0+=k1; x1+=ks2+4u;
  x0+=x1; x1=rotl_(x1,13); x1^=x0;
  x0+=x1; x1=rotl_(x1,15); x1^=x0;
  x0+=x1; x1=rotl_(x1,26); x1^=x0;
  x0+=x1; x1=rotl_(x1, 6); x1^=x0;
  x0+=ks2; x1+=k0+5u;
  o0 = x0; o1 = x1;
}

__global__ __launch_bounds__(BLKT, 2) void speller_kernel(
    const float* __restrict__ seq, const int* __restrict__ slen,
    const float* __restrict__ Ech, const float* __restrict__ Wkey,
    const float* __restrict__ Wval, const float* __restrict__ bval,
    const float* __restrict__ Wih, const float* __restrict__ Whh,
    const float* __restrict__ bih, const float* __restrict__ bhh,
    const float* __restrict__ Wcdn, const float* __restrict__ bcdn,
    int* __restrict__ out, float* __restrict__ ws, int MS, int CH)
{
  const int tid = threadIdx.x;
  const int bid = blockIdx.x;
  const int gid = bid*BLKT + tid;

  // ---- workspace layout ----
  float* biasf = ws;                         // [2048]  b_ih + b_hh          (cached)
  float* h0    = biasf + 2048;               // [NB*HH]                      (coherent)
  float* h1    = h0 + NB*HH;                 // [NB*HH]                      (coherent)
  float* cb    = h1 + NB*HH;                 // [NB*HH]  block-private       (cached)
  float* ctx   = cb + NB*HH;                 // [NB*HH]                      (coherent)
  float* pm    = ctx + NB*HH;                // [NB*MS]                      (coherent)
  float* ps    = pm + NB*MS;                 // [NB*MS]                      (coherent)
  float* pacc  = ps + NB*MS;                 // [NB*MS*HH]                   (coherent)
  int*   iw    = (int*)(pacc + (size_t)NB*MS*HH);
  int*   yv    = iw;                          // [64]                        (coherent)
  int*   pref  = iw + 64;                     // [65]  chunk prefix          (cached, write-once)
  int*   bar   = iw + 192;                    // barrier area (memset 0 per launch)

  __shared__ float sXs[128*65];
  __shared__ float sRed[8*8*64];
  __shared__ float sGate[8*64];
  __shared__ float sAcc[8*512];
  __shared__ float sQt[512];
  __shared__ float sHb[512];
  __shared__ float sWm[8], sWs[8], sWf[8];
  __shared__ float sEb[512];
  __shared__ float sHs[512];
  __shared__ float sCt[512];
  __shared__ float sP[34*8];
  __shared__ float sZ[34];
  __shared__ float sAm[32], sAs[32], sAf[32];
  __shared__ float sSc[2];
  __shared__ int   sPref[65];
  __shared__ int   sLenA[64];
  __shared__ int   sYv[64];

  // ---- hierarchical grid barrier, NO L2 fences in the fast path ----
  // Sound because hipcc drains vmcnt(0) before s_barrier: all waves' coherent
  // (sc0 sc1) stores are acked at the coherence point before tid0 arrives.
  int epoch = 0;
  auto gsync = [&](bool full){
    __syncthreads();
    epoch++;
    if (tid == 0){
      if (full) __threadfence();   // one-time: push P0's cached init to memory
      const int g = bid >> 5;      // 8 groups of 32 blocks
      int r = __hip_atomic_fetch_add(&bar[32+g*32], 1, __ATOMIC_RELAXED, __HIP_MEMORY_SCOPE_AGENT);
      if (r == epoch*32 - 1){
        int rr = __hip_atomic_fetch_add(&bar[0], 1, __ATOMIC_RELAXED, __HIP_MEMORY_SCOPE_AGENT);
        if (rr == epoch*8 - 1){
          #pragma unroll
          for (int i=0;i<8;i++)
            __hip_atomic_store(&bar[288+i*32], epoch, __ATOMIC_RELAXED, __HIP_MEMORY_SCOPE_AGENT);
        } else {
          while (__hip_atomic_load(&bar[288+g*32], __ATOMIC_RELAXED, __HIP_MEMORY_SCOPE_AGENT) < epoch)
            __builtin_amdgcn_s_sleep(2);
        }
      } else {
        while (__hip_atomic_load(&bar[288+g*32], __ATOMIC_RELAXED, __HIP_MEMORY_SCOPE_AGENT) < epoch)
          __builtin_amdgcn_s_sleep(2);
      }
      if (full) __threadfence();   // one-time: invalidate so cached readers see init
    }
    __syncthreads();
  };

  // ================= P0: one-time precompute =================
  {
    if (gid < NB*HH){ h0[gid]=0.f; h1[gid]=0.f; cb[gid]=0.f; }
    if (gid < NB) yv[gid] = 0;  // SOS
    if (gid < 2048) biasf[gid] = bih[gid] + bhh[gid];
    if (gid == 0){
      int acc = 0; pref[0] = 0;
      for (int b=0;b<NB;b++){
        int ln = slen[b]; if (ln < 1) ln = 1; if (ln > LL) ln = LL;
        acc += (ln + CH - 1)/CH;
        pref[b+1] = acc;
      }
    }
  }

  // ================= phase lambdas (arithmetic identical to verified R2/R4/R5) =================

  // A: gates = Wih*[emb(y); ctx] + Whh*h + biasf ; LSTM update -> c, hw
  auto phaseA = [&](const float* hr, float* hw){
    const int k0 = bid*2;
    const int w = tid >> 6, lane = tid & 63;
    if (tid < 64) sYv[tid] = LDC(&yv[tid]);
    float acc[8];
    #pragma unroll
    for (int jj=0;jj<8;jj++) acc[jj]=0.f;
    for (int kt=0; kt<12; kt++){
      __syncthreads();
      #pragma unroll
      for (int r=0;r<16;r++){
        int e = r*512 + tid;
        int b = e >> 7, kk = e & 127;
        int mm = kt*128 + kk;
        float v;
        if (kt < 4)      v = Ech[(size_t)sYv[b]*HH + mm];
        else if (kt < 8) v = LDC(&ctx[b*HH + (mm-512)]);
        else             v = LDC(&hr[b*HH + (mm-1024)]);
        sXs[kk*65 + b] = v;
      }
      __syncthreads();
      const float* wrow[8];
      #pragma unroll
      for (int jj=0;jj<8;jj++){
        int j = (jj>>1)*512 + k0 + (jj&1);
        if (kt < 8) wrow[jj] = Wih + (size_t)j*1024 + kt*128;
        else        wrow[jj] = Whh + (size_t)j*512  + (kt-8)*128;
      }
      #pragma unroll
      for (int it=0; it<4; it++){
        int kkb = w*16 + it*4;
        float x0 = sXs[(kkb+0)*65 + lane];
        float x1 = sXs[(kkb+1)*65 + lane];
        float x2 = sXs[(kkb+2)*65 + lane];
        float x3 = sXs[(kkb+3)*65 + lane];
        #pragma unroll
        for (int jj=0;jj<8;jj++){
          float4 wv = *(const float4*)(wrow[jj] + kkb);
          acc[jj] += wv.x*x0; acc[jj] += wv.y*x1;
          acc[jj] += wv.z*x2; acc[jj] += wv.w*x3;
        }
      }
    }
    __syncthreads();
    #pragma unroll
    for (int jj=0;jj<8;jj++) sRed[(w*8+jj)*64 + lane] = acc[jj];
    __syncthreads();
    {
      int jj2 = tid >> 6, b2 = tid & 63;
      int j = (jj2>>1)*512 + k0 + (jj2&1);
      float g = biasf[j];
      #pragma unroll
      for (int w2=0; w2<8; w2++) g += sRed[(w2*8+jj2)*64 + b2];
      sGate[jj2*64 + b2] = g;
    }
    __syncthreads();
    if (tid < 128){
      int k01 = tid >> 6, b3 = tid & 63;
      int k = k0 + k01;
      float gi = sGate[(0+k01)*64 + b3];
      float gf = sGate[(2+k01)*64 + b3];
      float gg = sGate[(4+k01)*64 + b3];
      float go = sGate[(6+k01)*64 + b3];
      float co = cb[b3*HH + k];                 // block-private: cached
      float cn = sigm_(gf)*co + sigm_(gi)*tanhf(gg);
      cb[b3*HH + k] = cn;
      STC(&hw[b3*HH + k], sigm_(go)*tanhf(cn)); // cross-block: coherent
    }
  };

  // C: static chunk range per block; per-batch qt recompute; streaming online-softmax
  auto phaseC = [&](const float* hr){
    if (tid < 65) sPref[tid] = pref[tid];
    if (tid < 64){ int ln = slen[tid]; if(ln<1)ln=1; if(ln>LL)ln=LL; sLenA[tid]=ln; }
    __syncthreads();
    const int nTot = sPref[64];
    const int w = tid >> 6, lane = tid & 63;
    const float SCALE = 1.0f / sqrtf(512.0f);
    const int start = (bid*nTot)/GRID, end = ((bid+1)*nTot)/GRID;
    int b = 0, bLast = -1;
    for (int c = start; c < end; ++c){
      while (sPref[b+1] <= c) b++;
      int slot = c - sPref[b];
      int l0 = slot * CH;
      int lend = min(l0 + CH, sLenA[b]);
      if (b != bLast){
        __syncthreads();
        sHb[tid] = LDC(&hr[b*HH + tid]);      // stage h[b] once (coherent)
        __syncthreads();
        // qt[b][tid] = sum_k Wkey[k][tid] * h[b][k]  (same order as verified phaseB)
        float a0 = 0.f;
        for (int k=0;k<512;k++)
          a0 += Wkey[(size_t)k*512 + tid] * sHb[k];
        sQt[tid] = a0;
        bLast = b;
      }
      __syncthreads();   // sQt visible; protects sAcc/sWf reuse across chunks
      const float4* qp = (const float4*)sQt;
      float4 qa = qp[lane], qb = qp[64+lane];
      float m = -FLT_MAX, ss = 0.f;
      float4 aA = make_float4(0,0,0,0), aB = make_float4(0,0,0,0);
      int l = l0 + w;
      float4 ea, eb;
      if (l < lend){
        const float4* rp = (const float4*)(seq + ((size_t)b*LL + l)*HH);
        ea = rp[lane]; eb = rp[64+lane];
      }
      while (l < lend){
        int ln2 = l + 8;
        float4 na, nb;
        if (ln2 < lend){   // 1-deep prefetch (no arithmetic reorder)
          const float4* rp2 = (const float4*)(seq + ((size_t)b*LL + ln2)*HH);
          na = rp2[lane]; nb = rp2[64+lane];
        }
        float d = ea.x*qa.x + ea.y*qa.y + ea.z*qa.z + ea.w*qa.w
                + eb.x*qb.x + eb.y*qb.y + eb.z*qb.z + eb.w*qb.w;
        #pragma unroll
        for (int msk=1; msk<64; msk<<=1) d += __shfl_xor(d, msk, 64);
        float sc = d * SCALE;
        float mn = fmaxf(m, sc);
        float r1 = expf(m - mn);
        float w1 = expf(sc - mn);
        ss = ss*r1 + w1;
        aA.x = aA.x*r1 + w1*ea.x; aA.y = aA.y*r1 + w1*ea.y;
        aA.z = aA.z*r1 + w1*ea.z; aA.w = aA.w*r1 + w1*ea.w;
        aB.x = aB.x*r1 + w1*eb.x; aB.y = aB.y*r1 + w1*eb.y;
        aB.z = aB.z*r1 + w1*eb.z; aB.w = aB.w*r1 + w1*eb.w;
        m = mn;
        ea = na; eb = nb; l = ln2;
      }
      ((float4*)(sAcc + w*512))[lane]    = aA;
      ((float4*)(sAcc + w*512))[64+lane] = aB;
      if (lane == 0){ sWm[w] = m; sWs[w] = ss; }
      __syncthreads();
      if (tid == 0){
        float M = sWm[0];
        #pragma unroll
        for (int i=1;i<8;i++) M = fmaxf(M, sWm[i]);
        float S = 0.f;
        #pragma unroll
        for (int i=0;i<8;i++){ float f = expf(sWm[i]-M); sWf[i]=f; S += sWs[i]*f; }
        STC(&pm[b*MS+slot], M); STC(&ps[b*MS+slot], S);
      }
      __syncthreads();
      {
        float v = 0.f;
        #pragma unroll
        for (int i=0;i<8;i++) v += sAcc[i*512 + tid] * sWf[i];
        STC(&pacc[((size_t)(b*MS+slot))*HH + tid], v);
      }
    }
  };

  // D: reduce -> ebar -> ctx ; logits ; gumbel sample
  auto phaseD = [&](int t, const float* hw){
    if (bid < 64){
      const int b = bid;
      const int nsl = pref[b+1] - pref[b];
      if (tid < nsl){ sAm[tid] = LDC(&pm[b*MS + tid]); sAs[tid] = LDC(&ps[b*MS + tid]); }
      __syncthreads();
      if (tid == 0){
        float M = sAm[0];
        for (int s=1;s<nsl;s++) M = fmaxf(M, sAm[s]);
        float S = 0.f;
        for (int s=0;s<nsl;s++){ float f = expf(sAm[s]-M); sAf[s] = f; S += sAs[s]*f; }
        sSc[0] = S;
      }
      __syncthreads();
      {
        float S = sSc[0];
        float v = 0.f;
        #pragma unroll 4
        for (int s=0;s<nsl;s++) v += LDC(&pacc[((size_t)(b*MS+s))*HH + tid]) * sAf[s];
        sEb[tid] = v / S;
        sHs[tid] = LDC(&hw[b*HH + tid]);
      }
      __syncthreads();
      {
        const float4* wr = (const float4*)(Wval + (size_t)tid*HH);
        const float4* er = (const float4*)sEb;
        float a = bval[tid];
        #pragma unroll 4
        for (int i=0;i<HH/4;i++){
          float4 w4 = wr[i], e4 = er[i];
          a += w4.x*e4.x; a += w4.y*e4.y; a += w4.z*e4.z; a += w4.w*e4.w;
        }
        sCt[tid] = a;
        STC(&ctx[b*HH + tid], a);
      }
      __syncthreads();
      if (t >= 0){
        if (tid < 34*8){
          int v = tid >> 3, ks = tid & 7;
          const float* wr = Wcdn + (size_t)v*1024 + ks*128;
          const float* xr = (ks < 4) ? (sHs + ks*128) : (sCt + (ks-4)*128);
          float p = 0.f;
          for (int i=0;i<128;i++) p += wr[i]*xr[i];
          sP[v*8+ks] = p;
        }
        __syncthreads();
        if (tid < 34){
          float lg = bcdn[tid];
          #pragma unroll
          for (int i=0;i<8;i++) lg += sP[tid*8+i];
          unsigned kk0, kk1; tf2x32_(0u, 42u, 0u, (unsigned)t, kk0, kk1);
          int idx = b*34 + tid;
          unsigned o0, o1, bits;
#if PARTITIONABLE
          tf2x32_(kk0, kk1, 0u, (unsigned)idx, o0, o1);
          bits = o0 ^ o1;
#else
          if (idx < 1088){ tf2x32_(kk0, kk1, (unsigned)idx, (unsigned)(idx+1088), o0, o1); bits = o0; }
          else           { tf2x32_(kk0, kk1, (unsigned)(idx-1088), (unsigned)idx, o0, o1); bits = o1; }
#endif
          float f = __uint_as_float((bits>>9) | 0x3f800000u) - 1.0f;
          float u = fmaxf(f, 1.17549435e-38f);
          float gmb = -logf(-logf(u));
          sZ[tid] = lg + gmb;
        }
        __syncthreads();
        if (tid == 0){
          float best = sZ[0]; int bi = 0;
          for (int v2=1; v2<34; v2++){ if (sZ[v2] > best){ best = sZ[v2]; bi = v2; } }
          STC(&yv[b], bi);
          out[b*TT + t] = bi;     // host-visible at kernel end (implicit release)
        }
      }
    }
  };

  // ================= schedule: 3 fence-free barriers per step =================
  gsync(true);              // full: flush P0 init to memory
  phaseC(h0);               // h0 == 0 -> qt == 0 bit-exactly -> uniform weights
  gsync(false);
  phaseD(-1, h0);           // ebar/ctx only, no sampling
  gsync(false);
  for (int t = 0; t < TT; t++){
    const float* hr = (t & 1) ? h1 : h0;
    float* hwv      = (t & 1) ? h0 : h1;
    phaseA(hr, hwv);
    gsync(false);
    phaseC(hwv);
    gsync(false);
    phaseD(t, hwv);
    gsync(false);
  }
}

extern "C" void kernel_launch(void* const* d_in, const int* in_sizes, int n_in,
                              void* d_out, int out_size, void* d_ws, size_t ws_size,
                              hipStream_t stream)
{
  const float* seq  = (const float*)d_in[0];
  const int*   slen = (const int*)d_in[1];
  const float* Ech  = (const float*)d_in[2];
  const float* Wkey = (const float*)d_in[3];
  // d_in[4] = b_key: cancels inside softmax, unused.
  const float* Wval = (const float*)d_in[5];
  const float* bval = (const float*)d_in[6];
  const float* Wih  = (const float*)d_in[7];
  const float* Whh  = (const float*)d_in[8];
  const float* bih  = (const float*)d_in[9];
  const float* bhh  = (const float*)d_in[10];
  const float* Wcdn = (const float*)d_in[11];
  const float* bcdn = (const float*)d_in[12];
  int*   out = (int*)d_out;
  float* ws  = (float*)d_ws;

  int MS = 32;
  size_t floats_total;
  while (true){
    floats_total = 2048 + 4*(size_t)NB*HH + (size_t)NB*MS*(2 + HH);
    size_t need = (floats_total + 1024)*4;
    if (need <= ws_size || MS == 1) break;
    MS >>= 1;
  }
  int CH = 2048 / MS;

  // zero the barrier area: ints at iw[192 .. 768)
  size_t bar_off = (floats_total + 192)*4;
  hipMemsetAsync((char*)d_ws + bar_off, 0, 576*4, stream);

  void* args[] = { (void*)&seq, (void*)&slen, (void*)&Ech, (void*)&Wkey,
                   (void*)&Wval, (void*)&bval, (void*)&Wih, (void*)&Whh,
                   (void*)&bih, (void*)&bhh, (void*)&Wcdn, (void*)&bcdn,
                   (void*)&out, (void*)&ws, (void*)&MS, (void*)&CH };
  hipLaunchCooperativeKernel((void*)speller_kernel, dim3(GRID), dim3(BLKT),
                             args, 0, stream);
}